// Round 13
// baseline (36457.001 us; speedup 1.0000x reference)
//
#include <hip/hip_runtime.h>

typedef unsigned short u16;
typedef unsigned int u32;
typedef unsigned long long u64;
typedef __attribute__((ext_vector_type(8))) short bf16x8;
typedef __attribute__((ext_vector_type(8))) unsigned short u16x8;
typedef __attribute__((ext_vector_type(4))) unsigned short u16x4;
typedef __attribute__((ext_vector_type(4))) float f32x4;

#define DI static __device__ __forceinline__

// ---------------- workspace layout (bytes) ----------------
constexpr size_t OFF_WKQ  = 0;                               // 256x256 f32  (scale*Wk@Wq^T)
constexpr size_t OFF_WVW  = OFF_WKQ  + 256*256*4;            // 256x128 f32  (Wv@W3)
constexpr size_t OFF_WB   = OFF_WVW  + 256*128*4;            // 256 f32      (scale*Wk@bq)
constexpr size_t OFF_BYV  = OFF_WB   + 256*4;                // 128 f32      (b3 + bv@W3)
constexpr size_t OFF_BG   = OFF_BYV  + 128*4;                // 2048 f32     (bih+bhh)
constexpr size_t OFF_W2T  = OFF_BG   + 2048*4;               // 256x512 bf16 (W2 transposed [n][k])
constexpr size_t OFF_W1F  = OFF_W2T  + 256*512*2;            // 16*4*64*8 bf16 (frag-swizzled W1)
constexpr size_t OFF_WIHF = OFF_W1F  + 16*4*64*8*2;          // 128*8*64*8 bf16
constexpr size_t OFF_WHHF = OFF_WIHF + 128*8*64*8*2;         // 128*16*64*8 bf16
constexpr size_t OFF_KT   = OFF_WHHF + 128*16*64*8*2;        // 64*1024*256 bf16
constexpr size_t OFF_VW   = OFF_KT   + (size_t)64*1024*256*2;// 64*1024*128 bf16
constexpr size_t OFF_S0   = OFF_VW   + (size_t)64*1024*128*2;// 65536 f32 (incl. mask bias)
constexpr size_t OFF_CB   = OFF_S0   + 65536*4;              // 64x512 f32 cell state
constexpr size_t OFF_HF   = OFF_CB   + 64*512*4;             // 64x512 f32 h (sc1, intra-launch)
constexpr size_t OFF_HFR  = OFF_HF   + 64*512*4;             // 2 x (16*4*64*8) bf16 h frags (ping-pong)
constexpr size_t OFF_SC   = OFF_HFR  + 2*16*4*64*8*2;        // 2 x 64x1024 f32 raw scores (ping-pong)
constexpr size_t OFF_PART = OFF_SC   + 2*64*1024*4;          // 2 x 64x8x130 f32 (ping-pong)
constexpr size_t OFF_DXG  = OFF_PART + 2*64*8*130*4;         // 64x256 f32 dx (sc1, intra-launch)
constexpr size_t OFF_HFL  = OFF_DXG  + 64*256*4;             // 64 x 16 u32 h-flags (64B stride)
constexpr size_t OFF_DXF  = OFF_HFL  + 64*16*4;              // 64 x 16 u32 dx-flags (64B stride)

DI float bf2f(u16 u){ unsigned int v = ((unsigned int)u) << 16; return __uint_as_float(v); }
DI u16 f2bf(float f){ unsigned int u = __float_as_uint(f); unsigned int r = (u + 0x7FFFu + ((u>>16)&1u)) >> 16; return (u16)r; }
DI float sigm(float x){ return 1.f/(1.f + __expf(-x)); }
DI float tanh_(float x){ return 1.f - 2.f/(__expf(2.f*x) + 1.f); }

// ---- agent-scope relaxed accessors (MALL-coherent) for intra-launch cross-WG data ----
DI float aldf(const float* p){ return __hip_atomic_load(p, __ATOMIC_RELAXED, __HIP_MEMORY_SCOPE_AGENT); }
DI void  astf(float* p, float v){ __hip_atomic_store(p, v, __ATOMIC_RELAXED, __HIP_MEMORY_SCOPE_AGENT); }
DI void  astu32(u32* p, u32 v){ __hip_atomic_store(p, v, __ATOMIC_RELAXED, __HIP_MEMORY_SCOPE_AGENT); }
DI u32   aldu32(const u32* p){ return __hip_atomic_load(p, __ATOMIC_RELAXED, __HIP_MEMORY_SCOPE_AGENT); }
DI void  astu64(u64* p, u64 v){ __hip_atomic_store(p, v, __ATOMIC_RELAXED, __HIP_MEMORY_SCOPE_AGENT); }

// frag slot for an A-operand element [row m][k]
DI int fragIdx(int m, int k){ return (((k>>5)*4 + (m>>4))*64 + ((m&15) | (((k>>3)&3)<<4)))*8 + (k&7); }

// ---------------- one-time weight prep ----------------
__global__ __launch_bounds__(256) void kPrep(char* ws,
    const float* W1, const float* Wih, const float* Whh, const float* W2,
    const float* Wq, const float* bq, const float* Wk, const float* bk,
    const float* Wv, const float* bv, const float* W3, const float* b3,
    const float* bih, const float* bhh, const float* c0, const float* h0)
{
  const int wg = blockIdx.x, tid = threadIdx.x;
  if (wg < 64) {                       // Wkq
    float* Wkq = (float*)(ws + OFF_WKQ);
    for (int rr = 0; rr < 4; ++rr) {
      const int e = wg*4 + rr;
      float acc = 0.f;
      for (int d = 0; d < 256; ++d) acc = fmaf(Wk[e*256+d], Wq[tid*256+d], acc);
      Wkq[e*256 + tid] = acc * 0.0625f;
    }
  } else if (wg < 96) {                // Wvw
    float* Wvw = (float*)(ws + OFF_WVW);
    if (tid < 128) {
      for (int rr = 0; rr < 8; ++rr) {
        const int e = (wg-64)*8 + rr;
        float acc = 0.f;
        for (int d = 0; d < 256; ++d) acc = fmaf(Wv[e*256+d], W3[d*128+tid], acc);
        Wvw[e*128 + tid] = acc;
      }
    }
  } else if (wg == 96) {               // wb, byv
    float* wb = (float*)(ws + OFF_WB);
    float acc = 0.f;
    for (int d = 0; d < 256; ++d) acc = fmaf(Wk[tid*256+d], bq[d], acc);
    wb[tid] = acc * 0.0625f;
    if (tid < 128) {
      float* byv = (float*)(ws + OFF_BYV);
      float a2 = b3[tid];
      for (int d = 0; d < 256; ++d) a2 = fmaf(bv[d], W3[d*128+tid], a2);
      byv[tid] = a2;
    }
  } else if (wg == 97) {               // bg; zero h/dx flags (replay determinism)
    float* bg = (float*)(ws + OFF_BG);
    for (int j = tid; j < 2048; j += 256) bg[j] = bih[j] + bhh[j];
    u32* fl = (u32*)(ws + OFF_HFL);
    for (int j = tid; j < 2048; j += 256) fl[j] = 0u;   // hflags(1024) + dxflags(1024)
  } else if (wg < 106) {               // W2 -> W2T bf16 [n][k]
    u16* W2T = (u16*)(ws + OFF_W2T);
    const int n0 = (wg - 98)*32;
    for (int nn = 0; nn < 32; ++nn) {
      const int n = n0 + nn;
      for (int k = tid; k < 512; k += 256) W2T[n*512 + k] = f2bf(W2[k*256 + n]);
    }
  } else if (wg < 122) {               // W1 frag swizzle
    u16* W1f = (u16*)(ws + OFF_W1F);
    const int nt2 = wg - 106;
    for (int idx = tid; idx < 4*512; idx += 256) {
      const int kt2 = idx >> 9, rem = idx & 511, lane = rem >> 3, i = rem & 7;
      const int k = kt2*32 + (lane>>4)*8 + i, n = nt2*16 + (lane&15);
      W1f[((nt2*4+kt2)*64+lane)*8+i] = f2bf(W1[k*256+n]);
    }
  } else if (wg < 250) {               // Wih frag swizzle
    u16* Wihf = (u16*)(ws + OFF_WIHF);
    const int nt = wg - 122;
    for (int idx = tid; idx < 8*512; idx += 256) {
      const int kt = idx >> 9, rem = idx & 511, lane = rem >> 3, i = rem & 7;
      const int k = kt*32 + (lane>>4)*8 + i, r = lane & 15;
      const int gcol = (r>>2)*512 + nt*4 + (r&3);
      Wihf[((nt*8+kt)*64+lane)*8+i] = f2bf(Wih[k*2048 + gcol]);
    }
  } else if (wg < 378) {               // Whh frag swizzle
    u16* Whhf = (u16*)(ws + OFF_WHHF);
    const int nt = wg - 250;
    for (int idx = tid; idx < 16*512; idx += 256) {
      const int kt = idx >> 9, rem = idx & 511, lane = rem >> 3, i = rem & 7;
      const int k = kt*32 + (lane>>4)*8 + i, r = lane & 15;
      const int gcol = (r>>2)*512 + nt*4 + (r&3);
      Whhf[((nt*16+kt)*64+lane)*8+i] = f2bf(Whh[k*2048 + gcol]);
    }
  } else if (wg < 410) {               // state init
    float* cb = (float*)(ws + OFF_CB);
    u16* hfr0 = (u16*)(ws + OFF_HFR);
    const int base = (wg - 378)*1024;
    for (int ii = tid; ii < 1024; ii += 256) {
      const int idx = base + ii, b = idx >> 9, j = idx & 511;
      cb[idx] = c0[idx];
      hfr0[fragIdx(b, j)] = f2bf(h0[idx]);
    }
  }
}

// ---------------- precompute kt, vw, s0 ----------------
__global__ __launch_bounds__(256) void kKTVW(char* __restrict__ ws, const float* __restrict__ hid_r,
                                             const float* __restrict__ in_mask)
{
  const int wg = blockIdx.x, tid = threadIdx.x;
  __shared__ float lh[256*36];
  const float* Wkq = (const float*)(ws + OFF_WKQ);
  const float* Wvw = (const float*)(ws + OFF_WVW);
  const float* wb  = (const float*)(ws + OFF_WB);
  u16* kt = (u16*)(ws + OFF_KT);
  u16* vw = (u16*)(ws + OFF_VW);
  float* s0 = (float*)(ws + OFF_S0);
  const size_t r0 = (size_t)wg * 32;
  for (int idx = tid; idx < 32*256; idx += 256) {
    const int e = idx & 255, r = idx >> 8;
    lh[e*36 + r] = hid_r[(r0 + r)*256 + e];
  }
  __syncthreads();
  float acc[32];
  #pragma unroll
  for (int r = 0; r < 32; ++r) acc[r] = 0.f;
  for (int e = 0; e < 256; ++e) {
    const float wv = Wkq[e*256 + tid];
    #pragma unroll
    for (int r4 = 0; r4 < 8; ++r4) {
      const float4 l4 = *(const float4*)&lh[e*36 + r4*4];
      acc[r4*4+0] = fmaf(l4.x, wv, acc[r4*4+0]);
      acc[r4*4+1] = fmaf(l4.y, wv, acc[r4*4+1]);
      acc[r4*4+2] = fmaf(l4.z, wv, acc[r4*4+2]);
      acc[r4*4+3] = fmaf(l4.w, wv, acc[r4*4+3]);
    }
  }
  for (int r = 0; r < 32; ++r) kt[(r0 + r)*256 + tid] = f2bf(acc[r]);
  if (tid < 128) {
    #pragma unroll
    for (int r = 0; r < 32; ++r) acc[r] = 0.f;
    for (int e = 0; e < 256; ++e) {
      const float wv = Wvw[e*128 + tid];
      #pragma unroll
      for (int r4 = 0; r4 < 8; ++r4) {
        const float4 l4 = *(const float4*)&lh[e*36 + r4*4];
        acc[r4*4+0] = fmaf(l4.x, wv, acc[r4*4+0]);
        acc[r4*4+1] = fmaf(l4.y, wv, acc[r4*4+1]);
        acc[r4*4+2] = fmaf(l4.z, wv, acc[r4*4+2]);
        acc[r4*4+3] = fmaf(l4.w, wv, acc[r4*4+3]);
      }
    }
    for (int r = 0; r < 32; ++r) vw[(r0 + r)*128 + tid] = f2bf(acc[r]);
  } else if (tid < 160) {
    const int r = tid - 128;
    float a3 = 0.f;
    for (int e = 0; e < 256; ++e) a3 = fmaf(lh[e*36 + r], wb[e], a3);
    s0[r0 + r] = a3 + (in_mask[r0 + r] == 0.f ? -1e9f : 0.f);
  }
}

// ---------------- LDS ----------------
struct ShmGates {
  union {
    u16 yfrag[16*64*8];                                   // 16KB: stages 1-2
    float gtile[64*32];                                   // 8KB: stages 3-4
    struct { float hstage[512]; float dxred[512]; } dxs;  // 4KB: dx phase
  } u;
  union {
    u16 afrag[32*64*8];                                   // 32KB: stages 2-3
    float lfac[64*8];                                     // stage 1
  } v;
};
struct ShmAttn { float mrg[16*132]; float dxl[256]; };    // aliases ShmGates.u
union Shm { ShmGates g; ShmAttn a; };

// ---------------- kStep: one launch per step (flag-DAG) ----------------
__global__ __launch_bounds__(512, 4) void kStep(char* __restrict__ ws, const float* __restrict__ init_in,
    const float* __restrict__ in_mask, const float* __restrict__ b1, const float* __restrict__ b2,
    float* __restrict__ dout, int s)
{
  const int wg = blockIdx.x, tid = threadIdx.x;
  __shared__ Shm sh;

  const float* part = (const float*)(ws + OFF_PART) + (size_t)((s+1)&1)*(64*8*130);  // step s-1
  float* partc = (float*)(ws + OFF_PART) + (size_t)(s&1)*(64*8*130);                 // step s
  const float* scp = (const float*)(ws + OFF_SC) + (size_t)((s+1)&1)*(64*1024);
  float* scc = (float*)(ws + OFF_SC) + (size_t)(s&1)*(64*1024);
  const float* byv = (const float*)(ws + OFF_BYV);
  float* HF = (float*)(ws + OFF_HF);
  float* dxg = (float*)(ws + OFF_DXG);
  u32* hfl = (u32*)(ws + OFF_HFL);
  u32* dxf = (u32*)(ws + OFF_DXF);
  const u32 epoch = (u32)s + 1u;

  int b, ch;
  if (wg < 64) { b = wg; ch = 7; }
  else { const int a = wg - 64; b = a / 7; ch = a % 7; }

  // ================= writer prologue: outputs for t = s-1 =================
  if (s > 0 && tid < 256) {
    float pm[8], pS[8], m = -1e30f;
    #pragma unroll
    for (int c = 0; c < 8; ++c) { pm[c] = part[(b*8+c)*130]; pS[c] = part[(b*8+c)*130+1]; m = fmaxf(m, pm[c]); }
    float Sv = 0.f;
    #pragma unroll
    for (int c = 0; c < 8; ++c) Sv += pS[c] * __expf(pm[c]-m);
    const float inv = 1.f / Sv;
    const int t = s - 1;
    if (tid < 128) {
      const int l = ch*128 + tid;
      float* attn = dout + (size_t)64*1024*128;
      __builtin_nontemporal_store(__expf(scp[b*1024 + l] - m) * inv,
                                  &attn[((size_t)b*1024 + t)*1024 + l]);
    } else if (ch == 0) {
      const int d0 = tid - 128;
      float a2 = 0.f;
      #pragma unroll
      for (int c = 0; c < 8; ++c) a2 += __expf(pm[c]-m) * part[(b*8+c)*130+2+d0];
      const float y = fmaxf(a2*inv + byv[d0], 0.f);
      __builtin_nontemporal_store(y * in_mask[b*1024 + t],
                                  &dout[((size_t)b*1024 + t)*128 + d0]);
    }
  }

  const int hl = tid & 31, unit = tid >> 5;

  if (wg < 64) {
    // ================= GATES (8-wave remap of R10 kA) =================
    // stage 1: y -> yfrag
    if (s == 0) {
      for (int idx = tid; idx < 64*128; idx += 512) {
        const int bb = idx >> 7, d0 = idx & 127;
        sh.g.u.yfrag[fragIdx(bb, d0)] = f2bf(init_in[bb*128 + d0]);
      }
    } else {
      if (tid < 64) {
        const int bb = tid;
        float pm[8], m = -1e30f;
        #pragma unroll
        for (int c = 0; c < 8; ++c) { pm[c] = part[(bb*8+c)*130]; m = fmaxf(m, pm[c]); }
        float Sv = 0.f, pf[8];
        #pragma unroll
        for (int c = 0; c < 8; ++c) { pf[c] = __expf(pm[c]-m); Sv += part[(bb*8+c)*130+1]*pf[c]; }
        const float inv = 1.f/Sv;
        #pragma unroll
        for (int c = 0; c < 8; ++c) sh.g.v.lfac[bb*8+c] = pf[c]*inv;
      }
      __syncthreads();
      for (int idx = tid; idx < 64*128; idx += 512) {
        const int bb = idx >> 7, d0 = idx & 127;
        float a2 = byv[d0];
        #pragma unroll
        for (int c = 0; c < 8; ++c) a2 += sh.g.v.lfac[bb*8+c]*part[(bb*8+c)*130+2+d0];
        sh.g.u.yfrag[fragIdx(bb, d0)] = f2bf(fmaxf(a2, 0.f));
      }
    }
    __syncthreads();
    const int w = tid >> 6, lane = tid & 63;
    // stage 2: a = relu(y@W1 + b1); 8 waves x 8 tiles
    {
      const u16* W1f = (const u16*)(ws + OFF_W1F);
      const int mt = w & 3, nh = w >> 2;
      for (int k = 0; k < 8; ++k) {
        const int nt2 = nh*8 + k;
        f32x4 acc = {0.f,0.f,0.f,0.f};
        #pragma unroll
        for (int kt2 = 0; kt2 < 4; ++kt2) {
          bf16x8 av = *(const bf16x8*)&sh.g.u.yfrag[((kt2*4+mt)*64+lane)*8];
          bf16x8 bv = *(const bf16x8*)&W1f[((nt2*4+kt2)*64+lane)*8];
          acc = __builtin_amdgcn_mfma_f32_16x16x32_bf16(av, bv, acc, 0, 0, 0);
        }
        const int col = nt2*16 + (lane&15);
        const float bb2 = b1[col];
        #pragma unroll
        for (int i = 0; i < 4; ++i) {
          const int bb = mt*16 + (lane>>4)*4 + i;
          sh.g.v.afrag[fragIdx(bb, col)] = f2bf(fmaxf(acc[i] + bb2, 0.f));
        }
      }
    }
    __syncthreads();
    // stage 3: gates 64x32; 8 waves (mt, ntile), full K per wave (no gmerge)
    {
      const u16* Wihf = (const u16*)(ws + OFF_WIHF);
      const u16* Whhf = (const u16*)(ws + OFF_WHHF);
      const u16* hfr = (const u16*)(ws + OFF_HFR) + (size_t)(s & 1)*(16*4*64*8);
      const int mt = w & 3, ntile = w >> 2;
      const int nt = wg*2 + ntile;
      f32x4 acc = {0.f,0.f,0.f,0.f};
      for (int kt = 0; kt < 8; ++kt) {
        bf16x8 av = *(const bf16x8*)&sh.g.v.afrag[((kt*4+mt)*64+lane)*8];
        bf16x8 bv = *(const bf16x8*)&Wihf[((nt*8+kt)*64+lane)*8];
        acc = __builtin_amdgcn_mfma_f32_16x16x32_bf16(av, bv, acc, 0, 0, 0);
      }
      for (int kt = 0; kt < 16; ++kt) {
        bf16x8 av = *(const bf16x8*)&hfr[((kt*4+mt)*64+lane)*8];
        bf16x8 bv = *(const bf16x8*)&Whhf[((nt*16+kt)*64+lane)*8];
        acc = __builtin_amdgcn_mfma_f32_16x16x32_bf16(av, bv, acc, 0, 0, 0);
      }
      __syncthreads();   // yfrag reads done -> gtile (aliases) writable
      const float* bg = (const float*)(ws + OFF_BG);
      const int r = lane & 15;
      const float bb2 = bg[(r>>2)*512 + nt*4 + (r&3)];
      #pragma unroll
      for (int i = 0; i < 4; ++i) {
        const int bb = mt*16 + (lane>>4)*4 + i;
        sh.g.u.gtile[bb*32 + ntile*16 + r] = acc[i] + bb2;
      }
    }
    __syncthreads();
    // stage 4: h,c update; publish h (sc1) + hfr (next launch)
    if (tid < 256) {
      const int bb = tid >> 2, jj2 = tid & 3;
      float* cb = (float*)(ws + OFF_CB);
      u16* hfw = (u16*)(ws + OFF_HFR) + (size_t)((s & 1) ^ 1)*(16*4*64*8);
      float hv[2];
      #pragma unroll
      for (int t2 = 0; t2 < 2; ++t2) {
        const int jj = jj2*2 + t2;
        const int j = wg*8 + jj;
        const int cb32 = bb*32 + (jj>>2)*16 + (jj&3);
        const float ig = sh.g.u.gtile[cb32 + 0];
        const float fg = sh.g.u.gtile[cb32 + 4];
        const float gg = sh.g.u.gtile[cb32 + 8];
        const float og = sh.g.u.gtile[cb32 + 12];
        const float cold = cb[bb*512 + j];
        const float cnew = sigm(fg)*cold + sigm(ig)*tanh_(gg);
        hv[t2] = sigm(og)*tanh_(cnew);
        cb[bb*512 + j] = cnew;
      }
      const int j0 = wg*8 + jj2*2;
      union { float f[2]; u64 u; } pk; pk.f[0] = hv[0]; pk.f[1] = hv[1];
      astu64((u64*)&HF[bb*512 + j0], pk.u);
      const u32 pw = (u32)f2bf(hv[0]) | ((u32)f2bf(hv[1]) << 16);
      *(u32*)&hfw[fragIdx(bb, j0)] = pw;
    }
    __syncthreads();                       // drains sc1 h stores
    if (tid == 0) astu32(&hfl[wg*16], epoch);
    // ---- wait for all h, gather h[b], dx once for batch b = wg ----
    if (tid < 64) {
      for (;;) {
        const u32 f = aldu32(&hfl[tid*16]);
        if (__all(f >= epoch)) break;
        __builtin_amdgcn_s_sleep(1);
      }
    }
    __syncthreads();
    sh.g.u.dxs.hstage[tid] = aldf(&HF[b*512 + tid]);   // gtile dead; aliases OK
    __syncthreads();
    float dxval = 0.f;
    {
      const u16* W2T = (const u16*)(ws + OFF_W2T);
      const int n = tid >> 1, kh = tid & 1;
      float acc = 0.f;
      for (int kk = 0; kk < 32; ++kk) {
        const int k = kh*256 + kk*8;
        const float4 h4a = *(const float4*)&sh.g.u.dxs.hstage[k];
        const float4 h4b = *(const float4*)&sh.g.u.dxs.hstage[k+4];
        const u16x8 wv = *(const u16x8*)(W2T + n*512 + k);
        acc = fmaf(h4a.x, bf2f(wv[0]), acc); acc = fmaf(h4a.y, bf2f(wv[1]), acc);
        acc = fmaf(h4a.z, bf2f(wv[2]), acc); acc = fmaf(h4a.w, bf2f(wv[3]), acc);
        acc = fmaf(h4b.x, bf2f(wv[4]), acc); acc = fmaf(h4b.y, bf2f(wv[5]), acc);
        acc = fmaf(h4b.z, bf2f(wv[6]), acc); acc = fmaf(h4b.w, bf2f(wv[7]), acc);
      }
      sh.g.u.dxs.dxred[tid] = acc;
      __syncthreads();
      if (tid < 256) dxval = fmaxf(sh.g.u.dxs.dxred[2*tid] + sh.g.u.dxs.dxred[2*tid+1] + b2[tid], 0.f);
    }
    __syncthreads();                       // dxred reads done -> attn region (aliases) writable
    if (tid < 256) {
      sh.a.dxl[tid] = dxval;
      astf(&dxg[b*256 + tid], dxval);
    }
    __syncthreads();                       // drains sc1 dx stores
    if (tid == 0) astu32(&dxf[b*16], epoch);
  } else {
    // ================= ATTN WG: spin for dx (KV preload issued around it) =================
    if (tid == 0) {
      while (aldu32(&dxf[b*16]) < epoch) __builtin_amdgcn_s_sleep(2);
    }
    __syncthreads();
    if (tid < 256) sh.a.dxl[tid] = aldf(&dxg[b*256 + tid]);
    __syncthreads();
  }

  // ================= attention over chunk ch (128 keys) =================
  {
    const u16* kt = (const u16*)(ws + OFF_KT);
    const u16* vw = (const u16*)(ws + OFF_VW);
    const float* s0 = (const float*)(ws + OFF_S0);
    u16x8 kvr[8]; u16x4 vvr[8]; float s0r[8];
    #pragma unroll
    for (int i = 0; i < 8; ++i) {
      const int l = ch*128 + i*16 + unit;
      const size_t row = (size_t)b*1024 + l;
      kvr[i] = *(const u16x8*)(kt + row*256 + hl*8);
      vvr[i] = *(const u16x4*)(vw + row*128 + hl*4);
      s0r[i] = s0[row];
    }
    float dxv[8];
    {
      const float4 d0 = *(const float4*)&sh.a.dxl[hl*8];
      const float4 d1 = *(const float4*)&sh.a.dxl[hl*8+4];
      dxv[0]=d0.x; dxv[1]=d0.y; dxv[2]=d0.z; dxv[3]=d0.w;
      dxv[4]=d1.x; dxv[5]=d1.y; dxv[6]=d1.z; dxv[7]=d1.w;
    }
    float sums[8];
    #pragma unroll
    for (int i = 0; i < 8; ++i) {
      float sum = 0.f;
      #pragma unroll
      for (int j2 = 0; j2 < 8; ++j2) sum = fmaf(bf2f(kvr[i][j2]), dxv[j2], sum);
      #pragma unroll
      for (int d = 1; d < 32; d <<= 1) sum += __shfl_xor(sum, d, 64);
      sums[i] = sum + s0r[i];
    }
    float keep = 0.f;
    #pragma unroll
    for (int i = 0; i < 8; ++i) if (hl == i) keep = sums[i];
    float m = sums[0];
    #pragma unroll
    for (int i = 1; i < 8; ++i) m = fmaxf(m, sums[i]);
    float S = 0.f, cx0 = 0.f, cx1 = 0.f, cx2 = 0.f, cx3 = 0.f;
    #pragma unroll
    for (int i = 0; i < 8; ++i) {
      const float e2 = __expf(sums[i] - m);
      S += e2;
      cx0 = fmaf(e2, bf2f(vvr[i][0]), cx0);
      cx1 = fmaf(e2, bf2f(vvr[i][1]), cx1);
      cx2 = fmaf(e2, bf2f(vvr[i][2]), cx2);
      cx3 = fmaf(e2, bf2f(vvr[i][3]), cx3);
    }
    if (hl < 8) scc[b*1024 + ch*128 + hl*16 + unit] = keep;
    sh.a.mrg[unit*132 + 4 + hl*4 + 0] = cx0;
    sh.a.mrg[unit*132 + 4 + hl*4 + 1] = cx1;
    sh.a.mrg[unit*132 + 4 + hl*4 + 2] = cx2;
    sh.a.mrg[unit*132 + 4 + hl*4 + 3] = cx3;
    if (hl == 0) { sh.a.mrg[unit*132] = m; sh.a.mrg[unit*132+1] = S; }
    __syncthreads();
    if (tid < 128) {
      float mg = -1e30f;
      for (int u = 0; u < 16; ++u) mg = fmaxf(mg, sh.a.mrg[u*132]);
      float Sg = 0.f, cx = 0.f;
      for (int u = 0; u < 16; ++u) {
        const float f = __expf(sh.a.mrg[u*132] - mg);
        Sg = fmaf(sh.a.mrg[u*132+1], f, Sg);
        cx = fmaf(f, sh.a.mrg[u*132 + 4 + tid], cx);
      }
      partc[(b*8+ch)*130 + 2 + tid] = cx;
      if (tid == 0) { partc[(b*8+ch)*130] = mg; partc[(b*8+ch)*130+1] = Sg; }
    }
  }
}

// ---------------- kWLast: writer for t=1023 ----------------
__global__ __launch_bounds__(1024) void kWLast(char* __restrict__ ws, const float* __restrict__ in_mask,
                                               float* __restrict__ dout)
{
  const int b = blockIdx.x, tid = threadIdx.x;
  const float* part = (const float*)(ws + OFF_PART) + (size_t)(1023&1)*(64*8*130);
  const float* sc   = (const float*)(ws + OFF_SC)   + (size_t)(1023&1)*(64*1024);
  float pm[8], pS[8], m = -1e30f;
  #pragma unroll
  for (int c = 0; c < 8; ++c) { pm[c] = part[(b*8+c)*130]; pS[c] = part[(b*8+c)*130+1]; m = fmaxf(m, pm[c]); }
  float Sv = 0.f;
  #pragma unroll
  for (int c = 0; c < 8; ++c) Sv += pS[c] * __expf(pm[c]-m);
  const float inv = 1.f / Sv;
  float* attn = dout + (size_t)64*1024*128;
  __builtin_nontemporal_store(__expf(sc[b*1024 + tid] - m) * inv,
                              &attn[((size_t)b*1024 + 1023)*1024 + tid]);
  if (tid < 128) {
    const float* byv = (const float*)(ws + OFF_BYV);
    float a2 = 0.f;
    #pragma unroll
    for (int c = 0; c < 8; ++c) a2 += __expf(pm[c]-m) * part[(b*8+c)*130+2+tid];
    const float y = fmaxf(a2*inv + byv[tid], 0.f);
    __builtin_nontemporal_store(y * in_mask[b*1024 + 1023],
                                &dout[((size_t)b*1024 + 1023)*128 + tid]);
  }
}

extern "C" void kernel_launch(void* const* d_in, const int* in_sizes, int n_in,
                              void* d_out, int out_size, void* d_ws, size_t ws_size,
                              hipStream_t stream)
{
  (void)in_sizes; (void)n_in; (void)out_size; (void)ws_size;
  const float* hid_r  = (const float*)d_in[0];
  const float* in_mask= (const float*)d_in[1];
  const float* init_in= (const float*)d_in[2];
  const float* h0     = (const float*)d_in[3];
  const float* c0     = (const float*)d_in[4];
  const float* W1     = (const float*)d_in[5];
  const float* b1     = (const float*)d_in[6];
  const float* Wih    = (const float*)d_in[7];
  const float* Whh    = (const float*)d_in[8];
  const float* bih    = (const float*)d_in[9];
  const float* bhh    = (const float*)d_in[10];
  const float* W2     = (const float*)d_in[11];
  const float* b2     = (const float*)d_in[12];
  const float* Wq     = (const float*)d_in[13];
  const float* bq     = (const float*)d_in[14];
  const float* Wk     = (const float*)d_in[15];
  const float* bk     = (const float*)d_in[16];
  const float* Wv     = (const float*)d_in[17];
  const float* bv     = (const float*)d_in[18];
  const float* W3     = (const float*)d_in[19];
  const float* b3     = (const float*)d_in[20];
  char* ws = (char*)d_ws;
  float* out = (float*)d_out;

  hipLaunchKernelGGL(kPrep, dim3(410), dim3(256), 0, stream, ws,
                     W1, Wih, Whh, W2, Wq, bq, Wk, bk, Wv, bv, W3, b3, bih, bhh, c0, h0);
  hipLaunchKernelGGL(kKTVW, dim3(2048), dim3(256), 0, stream, ws, hid_r, in_mask);
  for (int s = 0; s < 1024; ++s) {
    hipLaunchKernelGGL(kStep, dim3(512), dim3(512), 0, stream, ws, init_in, in_mask, b1, b2, out, s);
  }
  hipLaunchKernelGGL(kWLast, dim3(64), dim3(1024), 0, stream, ws, in_mask, out);
}

// Round 14
// 33573.520 us; speedup vs baseline: 1.0859x; 1.0859x over previous
//
#include <hip/hip_runtime.h>

typedef unsigned short u16;
typedef unsigned int u32;
typedef __attribute__((ext_vector_type(8))) short bf16x8;
typedef __attribute__((ext_vector_type(8))) unsigned short u16x8;
typedef __attribute__((ext_vector_type(4))) unsigned short u16x4;
typedef __attribute__((ext_vector_type(4))) float f32x4;

#define DI static __device__ __forceinline__

// ---------------- workspace layout (bytes) ----------------
constexpr size_t OFF_WKQ  = 0;                               // 256x256 f32  (scale*Wk@Wq^T)
constexpr size_t OFF_WVW  = OFF_WKQ  + 256*256*4;            // 256x128 f32  (Wv@W3)
constexpr size_t OFF_WB   = OFF_WVW  + 256*128*4;            // 256 f32      (scale*Wk@bq)
constexpr size_t OFF_BYV  = OFF_WB   + 256*4;                // 128 f32      (b3 + bv@W3)
constexpr size_t OFF_BG   = OFF_BYV  + 128*4;                // 2048 f32     (bih+bhh)
constexpr size_t OFF_W2T  = OFF_BG   + 2048*4;               // 256x512 bf16 (W2 transposed [n][k])
constexpr size_t OFF_W1F  = OFF_W2T  + 256*512*2;            // 16*4*64*8 bf16 (frag-swizzled W1)
constexpr size_t OFF_WIHF = OFF_W1F  + 16*4*64*8*2;          // 128*8*64*8 bf16
constexpr size_t OFF_WHHF = OFF_WIHF + 128*8*64*8*2;         // 128*16*64*8 bf16
constexpr size_t OFF_KT   = OFF_WHHF + 128*16*64*8*2;        // 64*1024*256 bf16
constexpr size_t OFF_VW   = OFF_KT   + (size_t)64*1024*256*2;// 64*1024*128 bf16
constexpr size_t OFF_S0   = OFF_VW   + (size_t)64*1024*128*2;// 65536 f32 (incl. mask bias)
constexpr size_t OFF_CB   = OFF_S0   + 65536*4;              // 64x512 f32 cell state
constexpr size_t OFF_HF   = OFF_CB   + 64*512*4;             // 64x512 f32 h
constexpr size_t OFF_HFR  = OFF_HF   + 64*512*4;             // 2 x (16*4*64*8) bf16 h frags (ping-pong)
constexpr size_t OFF_SC   = OFF_HFR  + 2*16*4*64*8*2;        // 2 x 64x1024 f32 raw scores (ping-pong)
constexpr size_t OFF_PART = OFF_SC   + 2*64*1024*4;          // 2 x 64x8x130 f32 (ping-pong)

DI float bf2f(u16 u){ unsigned int v = ((unsigned int)u) << 16; return __uint_as_float(v); }
DI u16 f2bf(float f){ unsigned int u = __float_as_uint(f); unsigned int r = (u + 0x7FFFu + ((u>>16)&1u)) >> 16; return (u16)r; }
DI float sigm(float x){ return 1.f/(1.f + __expf(-x)); }
DI float tanh_(float x){ return 1.f - 2.f/(__expf(2.f*x) + 1.f); }

// frag slot for an A-operand element [row m][k]
DI int fragIdx(int m, int k){ return (((k>>5)*4 + (m>>4))*64 + ((m&15) | (((k>>3)&3)<<4)))*8 + (k&7); }

// ---------------- one-time weight prep ----------------
__global__ __launch_bounds__(256) void kPrep(char* ws,
    const float* W1, const float* Wih, const float* Whh, const float* W2,
    const float* Wq, const float* bq, const float* Wk, const float* bk,
    const float* Wv, const float* bv, const float* W3, const float* b3,
    const float* bih, const float* bhh, const float* c0, const float* h0)
{
  const int wg = blockIdx.x, tid = threadIdx.x;
  if (wg < 64) {
    float* Wkq = (float*)(ws + OFF_WKQ);
    for (int rr = 0; rr < 4; ++rr) {
      const int e = wg*4 + rr;
      float acc = 0.f;
      for (int d = 0; d < 256; ++d) acc = fmaf(Wk[e*256+d], Wq[tid*256+d], acc);
      Wkq[e*256 + tid] = acc * 0.0625f;
    }
  } else if (wg < 96) {
    float* Wvw = (float*)(ws + OFF_WVW);
    if (tid < 128) {
      for (int rr = 0; rr < 8; ++rr) {
        const int e = (wg-64)*8 + rr;
        float acc = 0.f;
        for (int d = 0; d < 256; ++d) acc = fmaf(Wv[e*256+d], W3[d*128+tid], acc);
        Wvw[e*128 + tid] = acc;
      }
    }
  } else if (wg == 96) {
    float* wb = (float*)(ws + OFF_WB);
    float acc = 0.f;
    for (int d = 0; d < 256; ++d) acc = fmaf(Wk[tid*256+d], bq[d], acc);
    wb[tid] = acc * 0.0625f;
    if (tid < 128) {
      float* byv = (float*)(ws + OFF_BYV);
      float a2 = b3[tid];
      for (int d = 0; d < 256; ++d) a2 = fmaf(bv[d], W3[d*128+tid], a2);
      byv[tid] = a2;
    }
  } else if (wg == 97) {
    float* bg = (float*)(ws + OFF_BG);
    for (int j = tid; j < 2048; j += 256) bg[j] = bih[j] + bhh[j];
  } else if (wg < 106) {               // W2 -> W2T bf16, [n][k]
    u16* W2T = (u16*)(ws + OFF_W2T);
    const int n0 = (wg - 98)*32;
    for (int nn = 0; nn < 32; ++nn) {
      const int n = n0 + nn;
      for (int k = tid; k < 512; k += 256) W2T[n*512 + k] = f2bf(W2[k*256 + n]);
    }
  } else if (wg < 122) {               // W1 frag swizzle
    u16* W1f = (u16*)(ws + OFF_W1F);
    const int nt2 = wg - 106;
    for (int idx = tid; idx < 4*512; idx += 256) {
      const int kt2 = idx >> 9, rem = idx & 511, lane = rem >> 3, i = rem & 7;
      const int k = kt2*32 + (lane>>4)*8 + i, n = nt2*16 + (lane&15);
      W1f[((nt2*4+kt2)*64+lane)*8+i] = f2bf(W1[k*256+n]);
    }
  } else if (wg < 250) {               // Wih frag swizzle
    u16* Wihf = (u16*)(ws + OFF_WIHF);
    const int nt = wg - 122;
    for (int idx = tid; idx < 8*512; idx += 256) {
      const int kt = idx >> 9, rem = idx & 511, lane = rem >> 3, i = rem & 7;
      const int k = kt*32 + (lane>>4)*8 + i, r = lane & 15;
      const int gcol = (r>>2)*512 + nt*4 + (r&3);
      Wihf[((nt*8+kt)*64+lane)*8+i] = f2bf(Wih[k*2048 + gcol]);
    }
  } else if (wg < 378) {               // Whh frag swizzle
    u16* Whhf = (u16*)(ws + OFF_WHHF);
    const int nt = wg - 250;
    for (int idx = tid; idx < 16*512; idx += 256) {
      const int kt = idx >> 9, rem = idx & 511, lane = rem >> 3, i = rem & 7;
      const int k = kt*32 + (lane>>4)*8 + i, r = lane & 15;
      const int gcol = (r>>2)*512 + nt*4 + (r&3);
      Whhf[((nt*16+kt)*64+lane)*8+i] = f2bf(Whh[k*2048 + gcol]);
    }
  } else if (wg < 410) {               // state init
    float* cb = (float*)(ws + OFF_CB);
    u16* hfr0 = (u16*)(ws + OFF_HFR);
    const int base = (wg - 378)*1024;
    for (int ii = tid; ii < 1024; ii += 256) {
      const int idx = base + ii, b = idx >> 9, j = idx & 511;
      cb[idx] = c0[idx];
      hfr0[fragIdx(b, j)] = f2bf(h0[idx]);
    }
  }
}

// ---------------- precompute kt, vw, s0 (mask bias folded in) ----------------
__global__ __launch_bounds__(256) void kKTVW(char* __restrict__ ws, const float* __restrict__ hid_r,
                                             const float* __restrict__ in_mask)
{
  const int wg = blockIdx.x, tid = threadIdx.x;
  __shared__ float lh[256*36];
  const float* Wkq = (const float*)(ws + OFF_WKQ);
  const float* Wvw = (const float*)(ws + OFF_WVW);
  const float* wb  = (const float*)(ws + OFF_WB);
  u16* kt = (u16*)(ws + OFF_KT);
  u16* vw = (u16*)(ws + OFF_VW);
  float* s0 = (float*)(ws + OFF_S0);
  const size_t r0 = (size_t)wg * 32;
  for (int idx = tid; idx < 32*256; idx += 256) {
    const int e = idx & 255, r = idx >> 8;
    lh[e*36 + r] = hid_r[(r0 + r)*256 + e];
  }
  __syncthreads();
  float acc[32];
  #pragma unroll
  for (int r = 0; r < 32; ++r) acc[r] = 0.f;
  for (int e = 0; e < 256; ++e) {
    const float wv = Wkq[e*256 + tid];
    #pragma unroll
    for (int r4 = 0; r4 < 8; ++r4) {
      const float4 l4 = *(const float4*)&lh[e*36 + r4*4];
      acc[r4*4+0] = fmaf(l4.x, wv, acc[r4*4+0]);
      acc[r4*4+1] = fmaf(l4.y, wv, acc[r4*4+1]);
      acc[r4*4+2] = fmaf(l4.z, wv, acc[r4*4+2]);
      acc[r4*4+3] = fmaf(l4.w, wv, acc[r4*4+3]);
    }
  }
  for (int r = 0; r < 32; ++r) kt[(r0 + r)*256 + tid] = f2bf(acc[r]);
  if (tid < 128) {
    #pragma unroll
    for (int r = 0; r < 32; ++r) acc[r] = 0.f;
    for (int e = 0; e < 256; ++e) {
      const float wv = Wvw[e*128 + tid];
      #pragma unroll
      for (int r4 = 0; r4 < 8; ++r4) {
        const float4 l4 = *(const float4*)&lh[e*36 + r4*4];
        acc[r4*4+0] = fmaf(l4.x, wv, acc[r4*4+0]);
        acc[r4*4+1] = fmaf(l4.y, wv, acc[r4*4+1]);
        acc[r4*4+2] = fmaf(l4.z, wv, acc[r4*4+2]);
        acc[r4*4+3] = fmaf(l4.w, wv, acc[r4*4+3]);
      }
    }
    for (int r = 0; r < 32; ++r) vw[(r0 + r)*128 + tid] = f2bf(acc[r]);
  } else if (tid < 160) {
    const int r = tid - 128;
    float a3 = 0.f;
    for (int e = 0; e < 256; ++e) a3 = fmaf(lh[e*36 + r], wb[e], a3);
    s0[r0 + r] = a3 + (in_mask[r0 + r] == 0.f ? -1e9f : 0.f);
  }
}

// ---------------- kA: gates only (64 WGs x 1024 thr) ----------------
__global__ __launch_bounds__(1024) void kA(char* __restrict__ ws, const float* __restrict__ init_in,
                                           const float* __restrict__ b1, int s)
{
  const int wg = blockIdx.x, tid = threadIdx.x;
  const float* part = (const float*)(ws + OFF_PART) + (size_t)((s+1)&1)*(64*8*130);
  const float* byv = (const float*)(ws + OFF_BYV);

  __shared__ union {
    u16 yfrag[16*64*8];
    struct { float gmerge[8*64*4]; float gtile[64*32]; } s3;
  } shmU;
  __shared__ union {
    u16 afrag[32*64*8];
    float lfac[64*8];
  } shmV;

  // stage 1: y -> yfrag
  if (s == 0) {
    for (int idx = tid; idx < 64*128; idx += 1024) {
      const int b = idx >> 7, d0 = idx & 127;
      shmU.yfrag[fragIdx(b, d0)] = f2bf(init_in[b*128 + d0]);
    }
  } else {
    if (tid < 64) {
      const int b = tid;
      float pm[8], m = -1e30f;
      #pragma unroll
      for (int c = 0; c < 8; ++c) { pm[c] = part[(b*8+c)*130]; m = fmaxf(m, pm[c]); }
      float Sv = 0.f, pf[8];
      #pragma unroll
      for (int c = 0; c < 8; ++c) { pf[c] = __expf(pm[c]-m); Sv += part[(b*8+c)*130+1]*pf[c]; }
      const float inv = 1.f/Sv;
      #pragma unroll
      for (int c = 0; c < 8; ++c) shmV.lfac[b*8+c] = pf[c]*inv;
    }
    __syncthreads();
    for (int idx = tid; idx < 64*128; idx += 1024) {
      const int b = idx >> 7, d0 = idx & 127;
      float a2 = byv[d0];
      #pragma unroll
      for (int c = 0; c < 8; ++c) a2 += shmV.lfac[b*8+c]*part[(b*8+c)*130+2+d0];
      shmU.yfrag[fragIdx(b, d0)] = f2bf(fmaxf(a2, 0.f));
    }
  }
  __syncthreads();
  const int w = tid >> 6, lane = tid & 63;
  // stage 2: a = relu(y@W1 + b1)
  {
    const u16* W1f = (const u16*)(ws + OFF_W1F);
    const int mt = w & 3, nb0 = w >> 2;
    for (int k = 0; k < 4; ++k) {
      const int nt2 = nb0 + k*4;
      f32x4 acc = {0.f,0.f,0.f,0.f};
      #pragma unroll
      for (int kt2 = 0; kt2 < 4; ++kt2) {
        bf16x8 av = *(const bf16x8*)&shmU.yfrag[((kt2*4+mt)*64+lane)*8];
        bf16x8 bv = *(const bf16x8*)&W1f[((nt2*4+kt2)*64+lane)*8];
        acc = __builtin_amdgcn_mfma_f32_16x16x32_bf16(av, bv, acc, 0, 0, 0);
      }
      const int col = nt2*16 + (lane&15);
      const float bb = b1[col];
      #pragma unroll
      for (int i = 0; i < 4; ++i) {
        const int b = mt*16 + (lane>>4)*4 + i;
        shmV.afrag[fragIdx(b, col)] = f2bf(fmaxf(acc[i] + bb, 0.f));
      }
    }
  }
  __syncthreads();
  // stage 3: gates 64x32
  {
    const u16* Wihf = (const u16*)(ws + OFF_WIHF);
    const u16* Whhf = (const u16*)(ws + OFF_WHHF);
    const u16* hfr = (const u16*)(ws + OFF_HFR) + (size_t)(s & 1)*(16*4*64*8);
    const int mt = w & 3, ntile = (w>>2) & 1, khalf = w >> 3;
    const int nt = wg*2 + ntile;
    f32x4 acc = {0.f,0.f,0.f,0.f};
    if (khalf == 0) {
      for (int kt = 0; kt < 8; ++kt) {
        bf16x8 av = *(const bf16x8*)&shmV.afrag[((kt*4+mt)*64+lane)*8];
        bf16x8 bv = *(const bf16x8*)&Wihf[((nt*8+kt)*64+lane)*8];
        acc = __builtin_amdgcn_mfma_f32_16x16x32_bf16(av, bv, acc, 0, 0, 0);
      }
      for (int kt = 0; kt < 4; ++kt) {
        bf16x8 av = *(const bf16x8*)&hfr[((kt*4+mt)*64+lane)*8];
        bf16x8 bv = *(const bf16x8*)&Whhf[((nt*16+kt)*64+lane)*8];
        acc = __builtin_amdgcn_mfma_f32_16x16x32_bf16(av, bv, acc, 0, 0, 0);
      }
    } else {
      for (int kt = 4; kt < 16; ++kt) {
        bf16x8 av = *(const bf16x8*)&hfr[((kt*4+mt)*64+lane)*8];
        bf16x8 bv = *(const bf16x8*)&Whhf[((nt*16+kt)*64+lane)*8];
        acc = __builtin_amdgcn_mfma_f32_16x16x32_bf16(av, bv, acc, 0, 0, 0);
      }
      #pragma unroll
      for (int i = 0; i < 4; ++i) shmU.s3.gmerge[((ntile*4+mt)*64+lane)*4+i] = acc[i];
    }
    __syncthreads();
    if (khalf == 0) {
      const float* bg = (const float*)(ws + OFF_BG);
      const int r = lane & 15;
      const float bb = bg[(r>>2)*512 + nt*4 + (r&3)];
      #pragma unroll
      for (int i = 0; i < 4; ++i) {
        const int b = mt*16 + (lane>>4)*4 + i;
        shmU.s3.gtile[b*32 + ntile*16 + r] = acc[i] + shmU.s3.gmerge[((ntile*4+mt)*64+lane)*4+i] + bb;
      }
    }
  }
  __syncthreads();
  // stage 4: h,c pointwise
  if (tid < 256) {
    const int b = tid >> 2, jj2 = tid & 3;
    float* cb = (float*)(ws + OFF_CB);
    float* hf = (float*)(ws + OFF_HF);
    u16* hfw = (u16*)(ws + OFF_HFR) + (size_t)((s & 1) ^ 1)*(16*4*64*8);
    float hv[2];
    #pragma unroll
    for (int t2 = 0; t2 < 2; ++t2) {
      const int jj = jj2*2 + t2;
      const int j = wg*8 + jj;
      const int cb32 = b*32 + (jj>>2)*16 + (jj&3);
      const float ig = shmU.s3.gtile[cb32 + 0];
      const float fg = shmU.s3.gtile[cb32 + 4];
      const float gg = shmU.s3.gtile[cb32 + 8];
      const float og = shmU.s3.gtile[cb32 + 12];
      const float cold = cb[b*512 + j];
      const float cnew = sigm(fg)*cold + sigm(ig)*tanh_(gg);
      hv[t2] = sigm(og)*tanh_(cnew);
      cb[b*512 + j] = cnew;
    }
    const int j0 = wg*8 + jj2*2;
    *(float2*)&hf[b*512 + j0] = make_float2(hv[0], hv[1]);
    const u32 pw = (u32)f2bf(hv[0]) | ((u32)f2bf(hv[1]) << 16);
    *(u32*)&hfw[fragIdx(b, j0)] = pw;
  }
}

// ---------------- kB: writer(s-1) + KV-issue + dx + attention (512 WGs x 512 thr) ----------------
__global__ __launch_bounds__(512, 4) void kB(char* __restrict__ ws, const float* __restrict__ in_mask,
                                             const float* __restrict__ b2, float* __restrict__ dout, int s)
{
  const int wg = blockIdx.x, tid = threadIdx.x;
  const int b = wg >> 3, ch = wg & 7;          // batch, 128-key chunk
  const int hl = tid & 31, unit = tid >> 5;    // lane, unit 0..15
  __shared__ union { float red[256*33]; float mrg[16*132]; } U;
  __shared__ float dxl[256];

  const u16* kt = (const u16*)(ws + OFF_KT);
  const u16* vw = (const u16*)(ws + OFF_VW);
  const float* s0 = (const float*)(ws + OFF_S0);
  const float* byv = (const float*)(ws + OFF_BYV);
  float* partc = (float*)(ws + OFF_PART) + (size_t)(s&1)*(64*8*130);
  float* scc   = (float*)(ws + OFF_SC)   + (size_t)(s&1)*(64*1024);

  // ---- (1) writer for step s-1: loads issue first, complete first (in-order vmcnt) ----
  if (s > 0 && tid < 256) {
    const float* partp = (const float*)(ws + OFF_PART) + (size_t)((s+1)&1)*(64*8*130);
    const float* scp   = (const float*)(ws + OFF_SC)   + (size_t)((s+1)&1)*(64*1024);
    const int t = s - 1;
    float pm[8], pS[8], m = -1e30f;
    #pragma unroll
    for (int c = 0; c < 8; ++c) { pm[c] = partp[(b*8+c)*130]; pS[c] = partp[(b*8+c)*130+1]; m = fmaxf(m, pm[c]); }
    float Sv = 0.f;
    #pragma unroll
    for (int c = 0; c < 8; ++c) Sv += pS[c] * __expf(pm[c]-m);
    const float inv = 1.f / Sv;
    if (tid < 128) {
      const int l = ch*128 + tid;
      float* attn = dout + (size_t)64*1024*128;
      __builtin_nontemporal_store(__expf(scp[b*1024 + l] - m) * inv,
                                  &attn[((size_t)b*1024 + t)*1024 + l]);
    } else if (ch == 0) {
      const int d0 = tid - 128;
      float a2 = 0.f;
      #pragma unroll
      for (int c = 0; c < 8; ++c) a2 += __expf(pm[c]-m) * partp[(b*8+c)*130+2+d0];
      const float y = fmaxf(a2*inv + byv[d0], 0.f);
      __builtin_nontemporal_store(y * in_mask[b*1024 + t],
                                  &dout[((size_t)b*1024 + t)*128 + d0]);
    }
  }

  // ---- (2) KV stream issue, pinned here via keep-alive asm (rule #17): the ~48MB/step miss
  //      stream's latency overlaps the dx phase below instead of serializing after it ----
  u16x8 kvr[8]; u16x4 vvr[8]; float s0r[8];
  #pragma unroll
  for (int i = 0; i < 8; ++i) {
    const int l = ch*128 + i*16 + unit;
    const size_t row = (size_t)b*1024 + l;
    kvr[i] = *(const u16x8*)(kt + row*256 + hl*8);
    vvr[i] = *(const u16x4*)(vw + row*128 + hl*4);
    s0r[i] = s0[row];
  }
  #pragma unroll
  for (int i = 0; i < 8; ++i) {
    asm volatile("" : "+v"(kvr[i]));
    asm volatile("" : "+v"(vvr[i]));
    asm volatile("" : "+v"(s0r[i]));
  }

  // ---- (3) dx = relu(h[b]@W2 + b2) ----
  {
    const float* hb = (const float*)(ws + OFF_HF) + b*512;
    const u16* W2T = (const u16*)(ws + OFF_W2T);
    float hreg[16];
    #pragma unroll
    for (int i = 0; i < 4; ++i) {
      const float4 h4 = *(const float4*)(hb + hl*16 + i*4);
      hreg[i*4+0] = h4.x; hreg[i*4+1] = h4.y; hreg[i*4+2] = h4.z; hreg[i*4+3] = h4.w;
    }
    #pragma unroll
    for (int j = 0; j < 16; ++j) {
      const int n = unit*16 + j;
      const u16x8 w0 = *(const u16x8*)(W2T + n*512 + hl*16);
      const u16x8 w1 = *(const u16x8*)(W2T + n*512 + hl*16 + 8);
      float acc = 0.f;
      #pragma unroll
      for (int i2 = 0; i2 < 8; ++i2) acc = fmaf(hreg[i2], bf2f(w0[i2]), acc);
      #pragma unroll
      for (int i2 = 0; i2 < 8; ++i2) acc = fmaf(hreg[8+i2], bf2f(w1[i2]), acc);
      U.red[n*33 + hl] = acc;
    }
  }
  __syncthreads();
  if (tid < 256) {
    float acc = 0.f;
    #pragma unroll
    for (int l = 0; l < 32; ++l) acc += U.red[tid*33 + l];
    dxl[tid] = fmaxf(acc + b2[tid], 0.f);
  }
  __syncthreads();

  // ---- (4) attention over this WG's 128-key chunk (KV already in registers) ----
  float dxv[8];
  {
    const float4 d0 = *(const float4*)&dxl[hl*8];
    const float4 d1 = *(const float4*)&dxl[hl*8+4];
    dxv[0]=d0.x; dxv[1]=d0.y; dxv[2]=d0.z; dxv[3]=d0.w;
    dxv[4]=d1.x; dxv[5]=d1.y; dxv[6]=d1.z; dxv[7]=d1.w;
  }
  float sums[8];
  #pragma unroll
  for (int i = 0; i < 8; ++i) {
    float sum = 0.f;
    #pragma unroll
    for (int j2 = 0; j2 < 8; ++j2) sum = fmaf(bf2f(kvr[i][j2]), dxv[j2], sum);
    #pragma unroll
    for (int d = 1; d < 32; d <<= 1) sum += __shfl_xor(sum, d, 64);
    sums[i] = sum + s0r[i];
  }
  float keep = 0.f;
  #pragma unroll
  for (int i = 0; i < 8; ++i) if (hl == i) keep = sums[i];
  float m = sums[0];
  #pragma unroll
  for (int i = 1; i < 8; ++i) m = fmaxf(m, sums[i]);
  float S = 0.f, cx0 = 0.f, cx1 = 0.f, cx2 = 0.f, cx3 = 0.f;
  #pragma unroll
  for (int i = 0; i < 8; ++i) {
    const float e2 = __expf(sums[i] - m);
    S += e2;
    cx0 = fmaf(e2, bf2f(vvr[i][0]), cx0);
    cx1 = fmaf(e2, bf2f(vvr[i][1]), cx1);
    cx2 = fmaf(e2, bf2f(vvr[i][2]), cx2);
    cx3 = fmaf(e2, bf2f(vvr[i][3]), cx3);
  }
  if (hl < 8) scc[b*1024 + ch*128 + hl*16 + unit] = keep;
  U.mrg[unit*132 + 4 + hl*4 + 0] = cx0;
  U.mrg[unit*132 + 4 + hl*4 + 1] = cx1;
  U.mrg[unit*132 + 4 + hl*4 + 2] = cx2;
  U.mrg[unit*132 + 4 + hl*4 + 3] = cx3;
  if (hl == 0) { U.mrg[unit*132] = m; U.mrg[unit*132+1] = S; }
  __syncthreads();
  if (tid < 128) {
    float mg = -1e30f;
    for (int u = 0; u < 16; ++u) mg = fmaxf(mg, U.mrg[u*132]);
    float Sg = 0.f, cx = 0.f;
    for (int u = 0; u < 16; ++u) {
      const float f = __expf(U.mrg[u*132] - mg);
      Sg = fmaf(U.mrg[u*132+1], f, Sg);
      cx = fmaf(f, U.mrg[u*132 + 4 + tid], cx);
    }
    partc[(b*8+ch)*130 + 2 + tid] = cx;
    if (tid == 0) { partc[(b*8+ch)*130] = mg; partc[(b*8+ch)*130+1] = Sg; }
  }
}

// ---------------- kWLast: writer for t=1023 ----------------
__global__ __launch_bounds__(1024) void kWLast(char* __restrict__ ws, const float* __restrict__ in_mask,
                                               float* __restrict__ dout)
{
  const int b = blockIdx.x, tid = threadIdx.x;
  const float* part = (const float*)(ws + OFF_PART) + (size_t)(1023&1)*(64*8*130);
  const float* sc   = (const float*)(ws + OFF_SC)   + (size_t)(1023&1)*(64*1024);
  float pm[8], pS[8], m = -1e30f;
  #pragma unroll
  for (int c = 0; c < 8; ++c) { pm[c] = part[(b*8+c)*130]; pS[c] = part[(b*8+c)*130+1]; m = fmaxf(m, pm[c]); }
  float Sv = 0.f;
  #pragma unroll
  for (int c = 0; c < 8; ++c) Sv += pS[c] * __expf(pm[c]-m);
  const float inv = 1.f / Sv;
  float* attn = dout + (size_t)64*1024*128;
  __builtin_nontemporal_store(__expf(sc[b*1024 + tid] - m) * inv,
                              &attn[((size_t)b*1024 + 1023)*1024 + tid]);
  if (tid < 128) {
    const float* byv = (const float*)(ws + OFF_BYV);
    float a2 = 0.f;
    #pragma unroll
    for (int c = 0; c < 8; ++c) a2 += __expf(pm[c]-m) * part[(b*8+c)*130+2+tid];
    const float y = fmaxf(a2*inv + byv[tid], 0.f);
    __builtin_nontemporal_store(y * in_mask[b*1024 + 1023],
                                &dout[((size_t)b*1024 + 1023)*128 + tid]);
  }
}

extern "C" void kernel_launch(void* const* d_in, const int* in_sizes, int n_in,
                              void* d_out, int out_size, void* d_ws, size_t ws_size,
                              hipStream_t stream)
{
  (void)in_sizes; (void)n_in; (void)out_size; (void)ws_size;
  const float* hid_r  = (const float*)d_in[0];
  const float* in_mask= (const float*)d_in[1];
  const float* init_in= (const float*)d_in[2];
  const float* h0     = (const float*)d_in[3];
  const float* c0     = (const float*)d_in[4];
  const float* W1     = (const float*)d_in[5];
  const float* b1     = (const float*)d_in[6];
  const float* Wih    = (const float*)d_in[7];
  const float* Whh    = (const float*)d_in[8];
  const float* bih    = (const float*)d_in[9];
  const float* bhh    = (const float*)d_in[10];
  const float* W2     = (const float*)d_in[11];
  const float* b2     = (const float*)d_in[12];
  const float* Wq     = (const float*)d_in[13];
  const float* bq     = (const float*)d_in[14];
  const float* Wk     = (const float*)d_in[15];
  const float* bk     = (const float*)d_in[16];
  const float* Wv     = (const float*)d_in[17];
  const float* bv     = (const float*)d_in[18];
  const float* W3     = (const float*)d_in[19];
  const float* b3     = (const float*)d_in[20];
  char* ws = (char*)d_ws;
  float* out = (float*)d_out;

  hipLaunchKernelGGL(kPrep, dim3(410), dim3(256), 0, stream, ws,
                     W1, Wih, Whh, W2, Wq, bq, Wk, bk, Wv, bv, W3, b3, bih, bhh, c0, h0);
  hipLaunchKernelGGL(kKTVW, dim3(2048), dim3(256), 0, stream, ws, hid_r, in_mask);
  for (int s = 0; s < 1024; ++s) {
    hipLaunchKernelGGL(kA, dim3(64), dim3(1024), 0, stream, ws, init_in, b1, s);
    hipLaunchKernelGGL(kB, dim3(512), dim3(512), 0, stream, ws, in_mask, b2, out, s);
  }
  hipLaunchKernelGGL(kWLast, dim3(64), dim3(1024), 0, stream, ws, in_mask, out);
}

// Round 15
// 29223.895 us; speedup vs baseline: 1.2475x; 1.1488x over previous
//
#include <hip/hip_runtime.h>

typedef unsigned short u16;
typedef unsigned int u32;
typedef __attribute__((ext_vector_type(8))) short bf16x8;
typedef __attribute__((ext_vector_type(8))) unsigned short u16x8;
typedef __attribute__((ext_vector_type(4))) unsigned short u16x4;
typedef __attribute__((ext_vector_type(4))) float f32x4;

#define DI static __device__ __forceinline__

// ---------------- workspace layout (bytes) ----------------
constexpr size_t OFF_WKQ  = 0;                               // 256x256 f32  (scale*Wk@Wq^T)
constexpr size_t OFF_WVW  = OFF_WKQ  + 256*256*4;            // 256x128 f32  (Wv@W3)
constexpr size_t OFF_WB   = OFF_WVW  + 256*128*4;            // 256 f32      (scale*Wk@bq)
constexpr size_t OFF_BYV  = OFF_WB   + 256*4;                // 128 f32      (b3 + bv@W3)
constexpr size_t OFF_BG   = OFF_BYV  + 128*4;                // 2048 f32     (bih+bhh)
constexpr size_t OFF_W2T  = OFF_BG   + 2048*4;               // 256x512 bf16 (W2 transposed [n][k])
constexpr size_t OFF_W1F  = OFF_W2T  + 256*512*2;            // 16*4*64*8 bf16 (frag-swizzled W1)
constexpr size_t OFF_WIHF = OFF_W1F  + 16*4*64*8*2;          // 128*8*64*8 bf16
constexpr size_t OFF_WHHF = OFF_WIHF + 128*8*64*8*2;         // 128*16*64*8 bf16
constexpr size_t OFF_KT   = OFF_WHHF + 128*16*64*8*2;        // 64*1024*256 bf16
constexpr size_t OFF_VW   = OFF_KT   + (size_t)64*1024*256*2;// 64*1024*128 bf16
constexpr size_t OFF_S0   = OFF_VW   + (size_t)64*1024*128*2;// 65536 f32 (incl. mask bias)
constexpr size_t OFF_CB   = OFF_S0   + 65536*4;              // 64x512 f32 cell state
constexpr size_t OFF_HF   = OFF_CB   + 64*512*4;             // 64x512 f32 h
constexpr size_t OFF_HFR  = OFF_HF   + 64*512*4;             // 2 x (16*4*64*8) bf16 h frags (ping-pong)
constexpr size_t OFF_SC   = OFF_HFR  + 2*16*4*64*8*2;        // 2 x 64x1024 f32 raw scores (ping-pong)
constexpr size_t OFF_PART = OFF_SC   + 2*64*1024*4;          // 2 x 64x8x130 f32 (m,S,ctx[128]) (ping-pong)

DI float bf2f(u16 u){ unsigned int v = ((unsigned int)u) << 16; return __uint_as_float(v); }
DI u16 f2bf(float f){ unsigned int u = __float_as_uint(f); unsigned int r = (u + 0x7FFFu + ((u>>16)&1u)) >> 16; return (u16)r; }
DI float sigm(float x){ return 1.f/(1.f + __expf(-x)); }
DI float tanh_(float x){ return 1.f - 2.f/(__expf(2.f*x) + 1.f); }

// frag slot for an A-operand element [row m][k]: lane=(m&15)|(((k>>3)&3)<<4), i=k&7, ktile=k>>5, mtile=m>>4
DI int fragIdx(int m, int k){ return (((k>>5)*4 + (m>>4))*64 + ((m&15) | (((k>>3)&3)<<4)))*8 + (k&7); }

// ---------------- one-time weight prep ----------------
__global__ __launch_bounds__(256) void kPrep(char* ws,
    const float* W1, const float* Wih, const float* Whh, const float* W2,
    const float* Wq, const float* bq, const float* Wk, const float* bk,
    const float* Wv, const float* bv, const float* W3, const float* b3,
    const float* bih, const float* bhh, const float* c0, const float* h0)
{
  const int wg = blockIdx.x, tid = threadIdx.x;
  if (wg < 64) {                       // Wkq[e][d] = scale * dot(Wk row e, Wq row d)
    float* Wkq = (float*)(ws + OFF_WKQ);
    for (int rr = 0; rr < 4; ++rr) {
      const int e = wg*4 + rr;
      float acc = 0.f;
      for (int d = 0; d < 256; ++d) acc = fmaf(Wk[e*256+d], Wq[tid*256+d], acc);
      Wkq[e*256 + tid] = acc * 0.0625f;
    }
  } else if (wg < 96) {                // Wvw[e][o] = dot(Wv row e, W3 col o)
    float* Wvw = (float*)(ws + OFF_WVW);
    if (tid < 128) {
      for (int rr = 0; rr < 8; ++rr) {
        const int e = (wg-64)*8 + rr;
        float acc = 0.f;
        for (int d = 0; d < 256; ++d) acc = fmaf(Wv[e*256+d], W3[d*128+tid], acc);
        Wvw[e*128 + tid] = acc;
      }
    }
  } else if (wg == 96) {               // wb, byv
    float* wb = (float*)(ws + OFF_WB);
    float acc = 0.f;
    for (int d = 0; d < 256; ++d) acc = fmaf(Wk[tid*256+d], bq[d], acc);
    wb[tid] = acc * 0.0625f;
    if (tid < 128) {
      float* byv = (float*)(ws + OFF_BYV);
      float a2 = b3[tid];
      for (int d = 0; d < 256; ++d) a2 = fmaf(bv[d], W3[d*128+tid], a2);
      byv[tid] = a2;
    }
  } else if (wg == 97) {               // bg = bih + bhh
    float* bg = (float*)(ws + OFF_BG);
    for (int j = tid; j < 2048; j += 256) bg[j] = bih[j] + bhh[j];
  } else if (wg < 106) {               // W2 -> W2T bf16, [n][k] layout
    u16* W2T = (u16*)(ws + OFF_W2T);
    const int n0 = (wg - 98)*32;
    for (int nn = 0; nn < 32; ++nn) {
      const int n = n0 + nn;
      for (int k = tid; k < 512; k += 256) W2T[n*512 + k] = f2bf(W2[k*256 + n]);
    }
  } else if (wg < 122) {               // W1 frag swizzle (B-operand)
    u16* W1f = (u16*)(ws + OFF_W1F);
    const int nt2 = wg - 106;
    for (int idx = tid; idx < 4*512; idx += 256) {
      const int kt2 = idx >> 9, rem = idx & 511, lane = rem >> 3, i = rem & 7;
      const int k = kt2*32 + (lane>>4)*8 + i, n = nt2*16 + (lane&15);
      W1f[((nt2*4+kt2)*64+lane)*8+i] = f2bf(W1[k*256+n]);
    }
  } else if (wg < 250) {               // Wih frag swizzle, gate-interleaved col permutation
    u16* Wihf = (u16*)(ws + OFF_WIHF);
    const int nt = wg - 122;
    for (int idx = tid; idx < 8*512; idx += 256) {
      const int kt = idx >> 9, rem = idx & 511, lane = rem >> 3, i = rem & 7;
      const int k = kt*32 + (lane>>4)*8 + i, r = lane & 15;
      const int gcol = (r>>2)*512 + nt*4 + (r&3);   // r: 0..3=i,4..7=f,8..11=g,12..15=o
      Wihf[((nt*8+kt)*64+lane)*8+i] = f2bf(Wih[k*2048 + gcol]);
    }
  } else if (wg < 378) {               // Whh frag swizzle
    u16* Whhf = (u16*)(ws + OFF_WHHF);
    const int nt = wg - 250;
    for (int idx = tid; idx < 16*512; idx += 256) {
      const int kt = idx >> 9, rem = idx & 511, lane = rem >> 3, i = rem & 7;
      const int k = kt*32 + (lane>>4)*8 + i, r = lane & 15;
      const int gcol = (r>>2)*512 + nt*4 + (r&3);
      Whhf[((nt*16+kt)*64+lane)*8+i] = f2bf(Whh[k*2048 + gcol]);
    }
  } else if (wg < 410) {               // state init: c0 -> cbuf, h0 -> hfrag[0]
    float* cb = (float*)(ws + OFF_CB);
    u16* hfr0 = (u16*)(ws + OFF_HFR);
    const int base = (wg - 378)*1024;
    for (int ii = tid; ii < 1024; ii += 256) {
      const int idx = base + ii, b = idx >> 9, j = idx & 511;
      cb[idx] = c0[idx];
      hfr0[fragIdx(b, j)] = f2bf(h0[idx]);
    }
  }
}

// ---------------- precompute kt, vw, s0 (mask bias folded in) ----------------
__global__ __launch_bounds__(256) void kKTVW(char* __restrict__ ws, const float* __restrict__ hid_r,
                                             const float* __restrict__ in_mask)
{
  const int wg = blockIdx.x, tid = threadIdx.x;
  __shared__ float lh[256*36];  // [e][r], padded to 36
  const float* Wkq = (const float*)(ws + OFF_WKQ);
  const float* Wvw = (const float*)(ws + OFF_WVW);
  const float* wb  = (const float*)(ws + OFF_WB);
  u16* kt = (u16*)(ws + OFF_KT);
  u16* vw = (u16*)(ws + OFF_VW);
  float* s0 = (float*)(ws + OFF_S0);
  const size_t r0 = (size_t)wg * 32;
  for (int idx = tid; idx < 32*256; idx += 256) {
    const int e = idx & 255, r = idx >> 8;
    lh[e*36 + r] = hid_r[(r0 + r)*256 + e];
  }
  __syncthreads();
  float acc[32];
  #pragma unroll
  for (int r = 0; r < 32; ++r) acc[r] = 0.f;
  for (int e = 0; e < 256; ++e) {
    const float wv = Wkq[e*256 + tid];
    #pragma unroll
    for (int r4 = 0; r4 < 8; ++r4) {
      const float4 l4 = *(const float4*)&lh[e*36 + r4*4];
      acc[r4*4+0] = fmaf(l4.x, wv, acc[r4*4+0]);
      acc[r4*4+1] = fmaf(l4.y, wv, acc[r4*4+1]);
      acc[r4*4+2] = fmaf(l4.z, wv, acc[r4*4+2]);
      acc[r4*4+3] = fmaf(l4.w, wv, acc[r4*4+3]);
    }
  }
  for (int r = 0; r < 32; ++r) kt[(r0 + r)*256 + tid] = f2bf(acc[r]);
  if (tid < 128) {
    #pragma unroll
    for (int r = 0; r < 32; ++r) acc[r] = 0.f;
    for (int e = 0; e < 256; ++e) {
      const float wv = Wvw[e*128 + tid];
      #pragma unroll
      for (int r4 = 0; r4 < 8; ++r4) {
        const float4 l4 = *(const float4*)&lh[e*36 + r4*4];
        acc[r4*4+0] = fmaf(l4.x, wv, acc[r4*4+0]);
        acc[r4*4+1] = fmaf(l4.y, wv, acc[r4*4+1]);
        acc[r4*4+2] = fmaf(l4.z, wv, acc[r4*4+2]);
        acc[r4*4+3] = fmaf(l4.w, wv, acc[r4*4+3]);
      }
    }
    for (int r = 0; r < 32; ++r) vw[(r0 + r)*128 + tid] = f2bf(acc[r]);
  } else if (tid < 160) {
    const int r = tid - 128;
    float a3 = 0.f;
    for (int e = 0; e < 256; ++e) a3 = fmaf(lh[e*36 + r], wb[e], a3);
    s0[r0 + r] = a3 + (in_mask[r0 + r] == 0.f ? -1e9f : 0.f);
  }
}

// ---------------- kA: gates WGs (0-63) + writer WGs (64-127)   (128 WGs x 1024 thr) ----------------
__global__ __launch_bounds__(1024) void kA(char* __restrict__ ws, const float* __restrict__ init_in,
                                           const float* __restrict__ in_mask, const float* __restrict__ b1,
                                           float* __restrict__ dout, int s)
{
  const int wg = blockIdx.x, tid = threadIdx.x;
  const float* part = (const float*)(ws + OFF_PART) + (size_t)((s+1)&1)*(64*8*130);
  const float* byv = (const float*)(ws + OFF_BYV);

  if (wg >= 64) {   // ---- writer WG: outputs for t = s-1 (runs on CUs the gates GEMM never uses) ----
    if (s == 0) return;
    const int b = wg - 64, t = s - 1;
    const float* scp = (const float*)(ws + OFF_SC) + (size_t)((s+1)&1)*(64*1024);
    float pm[8], pS[8], m = -1e30f;
    #pragma unroll
    for (int c = 0; c < 8; ++c) { pm[c] = part[(b*8+c)*130]; pS[c] = part[(b*8+c)*130+1]; m = fmaxf(m, pm[c]); }
    float Sv = 0.f;
    #pragma unroll
    for (int c = 0; c < 8; ++c) Sv += pS[c] * __expf(pm[c]-m);
    const float inv = 1.f / Sv;
    float* attn = dout + (size_t)64*1024*128;
    __builtin_nontemporal_store(__expf(scp[b*1024 + tid] - m) * inv,
                                &attn[((size_t)b*1024 + t)*1024 + tid]);
    if (tid < 128) {
      float a2 = 0.f;
      #pragma unroll
      for (int c = 0; c < 8; ++c) a2 += __expf(pm[c]-m) * part[(b*8+c)*130+2+tid];
      const float y = fmaxf(a2*inv + byv[tid], 0.f);
      __builtin_nontemporal_store(y * in_mask[b*1024 + t],
                                  &dout[((size_t)b*1024 + t)*128 + tid]);
    }
    return;
  }

  // ---- gates WG ----
  __shared__ union {
    u16 yfrag[16*64*8];                                       // stages 1-2 (16 KB)
    struct { float gmerge[8*64*4]; float gtile[64*32]; } s3;  // stages 3-4 (16 KB)
  } shmU;
  __shared__ union {
    u16 afrag[32*64*8];                                       // stages 2-3 (32 KB)
    float lfac[64*8];                                         // stage 1 only
  } shmV;

  // stage 1: y -> yfrag (bf16 A-operand layout)
  if (s == 0) {
    for (int idx = tid; idx < 64*128; idx += 1024) {
      const int b = idx >> 7, d0 = idx & 127;
      shmU.yfrag[fragIdx(b, d0)] = f2bf(init_in[b*128 + d0]);
    }
  } else {
    if (tid < 64) {
      const int b = tid;
      float pm[8], m = -1e30f;
      #pragma unroll
      for (int c = 0; c < 8; ++c) { pm[c] = part[(b*8+c)*130]; m = fmaxf(m, pm[c]); }
      float Sv = 0.f, pf[8];
      #pragma unroll
      for (int c = 0; c < 8; ++c) { pf[c] = __expf(pm[c]-m); Sv += part[(b*8+c)*130+1]*pf[c]; }
      const float inv = 1.f/Sv;
      #pragma unroll
      for (int c = 0; c < 8; ++c) shmV.lfac[b*8+c] = pf[c]*inv;
    }
    __syncthreads();
    for (int idx = tid; idx < 64*128; idx += 1024) {
      const int b = idx >> 7, d0 = idx & 127;
      float a2 = byv[d0];
      #pragma unroll
      for (int c = 0; c < 8; ++c) a2 += shmV.lfac[b*8+c]*part[(b*8+c)*130+2+d0];
      shmU.yfrag[fragIdx(b, d0)] = f2bf(fmaxf(a2, 0.f));
    }
  }
  __syncthreads();
  const int w = tid >> 6, lane = tid & 63;
  // stage 2: a = relu(y@W1 + b1); 16 waves cover 64 (mt,nt2) tiles
  {
    const u16* W1f = (const u16*)(ws + OFF_W1F);
    const int mt = w & 3, nb0 = w >> 2;
    for (int k = 0; k < 4; ++k) {
      const int nt2 = nb0 + k*4;
      f32x4 acc = {0.f,0.f,0.f,0.f};
      #pragma unroll
      for (int kt2 = 0; kt2 < 4; ++kt2) {
        bf16x8 av = *(const bf16x8*)&shmU.yfrag[((kt2*4+mt)*64+lane)*8];
        bf16x8 bv = *(const bf16x8*)&W1f[((nt2*4+kt2)*64+lane)*8];
        acc = __builtin_amdgcn_mfma_f32_16x16x32_bf16(av, bv, acc, 0, 0, 0);
      }
      const int col = nt2*16 + (lane&15);
      const float bb = b1[col];
      #pragma unroll
      for (int i = 0; i < 4; ++i) {
        const int b = mt*16 + (lane>>4)*4 + i;
        shmV.afrag[fragIdx(b, col)] = f2bf(fmaxf(acc[i] + bb, 0.f));
      }
    }
  }
  __syncthreads();
  // stage 3: gates 64x32 tile = a@Wih + h@Whh + bg; 16 waves: (mt, ntile, khalf)
  {
    const u16* Wihf = (const u16*)(ws + OFF_WIHF);
    const u16* Whhf = (const u16*)(ws + OFF_WHHF);
    const u16* hfr = (const u16*)(ws + OFF_HFR) + (size_t)(s & 1)*(16*4*64*8);
    const int mt = w & 3, ntile = (w>>2) & 1, khalf = w >> 3;
    const int nt = wg*2 + ntile;
    f32x4 acc = {0.f,0.f,0.f,0.f};
    if (khalf == 0) {
      for (int kt = 0; kt < 8; ++kt) {
        bf16x8 av = *(const bf16x8*)&shmV.afrag[((kt*4+mt)*64+lane)*8];
        bf16x8 bv = *(const bf16x8*)&Wihf[((nt*8+kt)*64+lane)*8];
        acc = __builtin_amdgcn_mfma_f32_16x16x32_bf16(av, bv, acc, 0, 0, 0);
      }
      for (int kt = 0; kt < 4; ++kt) {
        bf16x8 av = *(const bf16x8*)&hfr[((kt*4+mt)*64+lane)*8];
        bf16x8 bv = *(const bf16x8*)&Whhf[((nt*16+kt)*64+lane)*8];
        acc = __builtin_amdgcn_mfma_f32_16x16x32_bf16(av, bv, acc, 0, 0, 0);
      }
    } else {
      for (int kt = 4; kt < 16; ++kt) {
        bf16x8 av = *(const bf16x8*)&hfr[((kt*4+mt)*64+lane)*8];
        bf16x8 bv = *(const bf16x8*)&Whhf[((nt*16+kt)*64+lane)*8];
        acc = __builtin_amdgcn_mfma_f32_16x16x32_bf16(av, bv, acc, 0, 0, 0);
      }
      #pragma unroll
      for (int i = 0; i < 4; ++i) shmU.s3.gmerge[((ntile*4+mt)*64+lane)*4+i] = acc[i];
    }
    __syncthreads();
    if (khalf == 0) {
      const float* bg = (const float*)(ws + OFF_BG);
      const int r = lane & 15;
      const float bb = bg[(r>>2)*512 + nt*4 + (r&3)];
      #pragma unroll
      for (int i = 0; i < 4; ++i) {
        const int b = mt*16 + (lane>>4)*4 + i;
        shmU.s3.gtile[b*32 + ntile*16 + r] = acc[i] + shmU.s3.gmerge[((ntile*4+mt)*64+lane)*4+i] + bb;
      }
    }
  }
  __syncthreads();
  // stage 4: h,c pointwise; 256 threads x 2 cols -> packed stores
  if (tid < 256) {
    const int b = tid >> 2, jj2 = tid & 3;
    float* cb = (float*)(ws + OFF_CB);
    float* hf = (float*)(ws + OFF_HF);
    u16* hfw = (u16*)(ws + OFF_HFR) + (size_t)((s & 1) ^ 1)*(16*4*64*8);
    float hv[2];
    #pragma unroll
    for (int t2 = 0; t2 < 2; ++t2) {
      const int jj = jj2*2 + t2;
      const int j = wg*8 + jj;
      const int cb32 = b*32 + (jj>>2)*16 + (jj&3);
      const float ig = shmU.s3.gtile[cb32 + 0];
      const float fg = shmU.s3.gtile[cb32 + 4];
      const float gg = shmU.s3.gtile[cb32 + 8];
      const float og = shmU.s3.gtile[cb32 + 12];
      const float cold = cb[b*512 + j];
      const float cnew = sigm(fg)*cold + sigm(ig)*tanh_(gg);
      hv[t2] = sigm(og)*tanh_(cnew);
      cb[b*512 + j] = cnew;
    }
    const int j0 = wg*8 + jj2*2;
    *(float2*)&hf[b*512 + j0] = make_float2(hv[0], hv[1]);
    const u32 pw = (u32)f2bf(hv[0]) | ((u32)f2bf(hv[1]) << 16);
    *(u32*)&hfw[fragIdx(b, j0)] = pw;
  }
}

// ---------------- kB: dx + flash attention, 128-key chunks (512 WGs x 512 thr, 2 WGs/CU) ----------------
__global__ __launch_bounds__(512, 4) void kB(char* __restrict__ ws, const float* __restrict__ b2, int s)
{
  const int wg = blockIdx.x, tid = threadIdx.x;
  const int b = wg >> 3, ch = wg & 7;          // batch, 128-key chunk
  const int hl = tid & 31, unit = tid >> 5;    // lane, unit 0..15
  __shared__ union { float red[256*33]; float mrg[16*132]; } U;
  __shared__ float dxl[256];

  const u16* kt = (const u16*)(ws + OFF_KT);
  const u16* vw = (const u16*)(ws + OFF_VW);
  const float* s0 = (const float*)(ws + OFF_S0);
  float* partc = (float*)(ws + OFF_PART) + (size_t)(s&1)*(64*8*130);
  float* scc   = (float*)(ws + OFF_SC)   + (size_t)(s&1)*(64*1024);

  // ---- issue full KV stream first: latency hides under dx; 2 WGs/CU keep the pipe busy ----
  u16x8 kvr[8]; u16x4 vvr[8]; float s0r[8];
  #pragma unroll
  for (int i = 0; i < 8; ++i) {
    const int l = ch*128 + i*16 + unit;        // unit-major: adjacent units read adjacent rows
    const size_t row = (size_t)b*1024 + l;
    kvr[i] = *(const u16x8*)(kt + row*256 + hl*8);
    vvr[i] = *(const u16x4*)(vw + row*128 + hl*4);
    s0r[i] = s0[row];
  }

  // ---- dx = relu(h[b]@W2 + b2): unit u computes cols u*16..u*16+15, lane hl owns k=hl*16..+15 ----
  {
    const float* hb = (const float*)(ws + OFF_HF) + b*512;
    const u16* W2T = (const u16*)(ws + OFF_W2T);
    float hreg[16];
    #pragma unroll
    for (int i = 0; i < 4; ++i) {
      const float4 h4 = *(const float4*)(hb + hl*16 + i*4);
      hreg[i*4+0] = h4.x; hreg[i*4+1] = h4.y; hreg[i*4+2] = h4.z; hreg[i*4+3] = h4.w;
    }
    #pragma unroll
    for (int j = 0; j < 16; ++j) {
      const int n = unit*16 + j;
      const u16x8 w0 = *(const u16x8*)(W2T + n*512 + hl*16);
      const u16x8 w1 = *(const u16x8*)(W2T + n*512 + hl*16 + 8);
      float acc = 0.f;
      #pragma unroll
      for (int i2 = 0; i2 < 8; ++i2) acc = fmaf(hreg[i2], bf2f(w0[i2]), acc);
      #pragma unroll
      for (int i2 = 0; i2 < 8; ++i2) acc = fmaf(hreg[8+i2], bf2f(w1[i2]), acc);
      U.red[n*33 + hl] = acc;   // pad-33: bank-conflict-free
    }
  }
  __syncthreads();
  if (tid < 256) {
    float acc = 0.f;
    #pragma unroll
    for (int l = 0; l < 32; ++l) acc += U.red[tid*33 + l];
    dxl[tid] = fmaxf(acc + b2[tid], 0.f);
  }
  __syncthreads();

  // ---- flash attention over this WG's 128-key chunk: batch-8 softmax per unit ----
  float dxv[8];
  {
    const float4 d0 = *(const float4*)&dxl[hl*8];
    const float4 d1 = *(const float4*)&dxl[hl*8+4];
    dxv[0]=d0.x; dxv[1]=d0.y; dxv[2]=d0.z; dxv[3]=d0.w;
    dxv[4]=d1.x; dxv[5]=d1.y; dxv[6]=d1.z; dxv[7]=d1.w;
  }
  float sums[8];
  #pragma unroll
  for (int i = 0; i < 8; ++i) {
    float sum = 0.f;
    #pragma unroll
    for (int j2 = 0; j2 < 8; ++j2) sum = fmaf(bf2f(kvr[i][j2]), dxv[j2], sum);
    #pragma unroll
    for (int d = 1; d < 32; d <<= 1) sum += __shfl_xor(sum, d, 64);
    sums[i] = sum + s0r[i];
  }
  float keep = 0.f;
  #pragma unroll
  for (int i = 0; i < 8; ++i) if (hl == i) keep = sums[i];
  float m = sums[0];
  #pragma unroll
  for (int i = 1; i < 8; ++i) m = fmaxf(m, sums[i]);
  float S = 0.f, cx0 = 0.f, cx1 = 0.f, cx2 = 0.f, cx3 = 0.f;
  #pragma unroll
  for (int i = 0; i < 8; ++i) {
    const float e2 = __expf(sums[i] - m);
    S += e2;
    cx0 = fmaf(e2, bf2f(vvr[i][0]), cx0);
    cx1 = fmaf(e2, bf2f(vvr[i][1]), cx1);
    cx2 = fmaf(e2, bf2f(vvr[i][2]), cx2);
    cx3 = fmaf(e2, bf2f(vvr[i][3]), cx3);
  }
  if (hl < 8) scc[b*1024 + ch*128 + hl*16 + unit] = keep;
  U.mrg[unit*132 + 4 + hl*4 + 0] = cx0;
  U.mrg[unit*132 + 4 + hl*4 + 1] = cx1;
  U.mrg[unit*132 + 4 + hl*4 + 2] = cx2;
  U.mrg[unit*132 + 4 + hl*4 + 3] = cx3;
  if (hl == 0) { U.mrg[unit*132] = m; U.mrg[unit*132+1] = S; }
  __syncthreads();
  if (tid < 128) {   // merge 16 unit-partials -> chunk partial
    float mg = -1e30f;
    for (int u = 0; u < 16; ++u) mg = fmaxf(mg, U.mrg[u*132]);
    float Sg = 0.f, cx = 0.f;
    for (int u = 0; u < 16; ++u) {
      const float f = __expf(U.mrg[u*132] - mg);
      Sg = fmaf(U.mrg[u*132+1], f, Sg);
      cx = fmaf(f, U.mrg[u*132 + 4 + tid], cx);
    }
    partc[(b*8+ch)*130 + 2 + tid] = cx;
    if (tid == 0) { partc[(b*8+ch)*130] = mg; partc[(b*8+ch)*130+1] = Sg; }
  }
}

// ---------------- kWLast: writer for t=1023 (64 WGs x 1024 thr) ----------------
__global__ __launch_bounds__(1024) void kWLast(char* __restrict__ ws, const float* __restrict__ in_mask,
                                               float* __restrict__ dout)
{
  const int b = blockIdx.x, tid = threadIdx.x;
  const float* part = (const float*)(ws + OFF_PART) + (size_t)(1023&1)*(64*8*130);
  const float* sc   = (const float*)(ws + OFF_SC)   + (size_t)(1023&1)*(64*1024);
  float pm[8], pS[8], m = -1e30f;
  #pragma unroll
  for (int c = 0; c < 8; ++c) { pm[c] = part[(b*8+c)*130]; pS[c] = part[(b*8+c)*130+1]; m = fmaxf(m, pm[c]); }
  float Sv = 0.f;
  #pragma unroll
  for (int c = 0; c < 8; ++c) Sv += pS[c] * __expf(pm[c]-m);
  const float inv = 1.f / Sv;
  float* attn = dout + (size_t)64*1024*128;
  __builtin_nontemporal_store(__expf(sc[b*1024 + tid] - m) * inv,
                              &attn[((size_t)b*1024 + 1023)*1024 + tid]);
  if (tid < 128) {
    const float* byv = (const float*)(ws + OFF_BYV);
    float a2 = 0.f;
    #pragma unroll
    for (int c = 0; c < 8; ++c) a2 += __expf(pm[c]-m) * part[(b*8+c)*130+2+tid];
    const float y = fmaxf(a2*inv + byv[tid], 0.f);
    __builtin_nontemporal_store(y * in_mask[b*1024 + 1023],
                                &dout[((size_t)b*1024 + 1023)*128 + tid]);
  }
}

extern "C" void kernel_launch(void* const* d_in, const int* in_sizes, int n_in,
                              void* d_out, int out_size, void* d_ws, size_t ws_size,
                              hipStream_t stream)
{
  (void)in_sizes; (void)n_in; (void)out_size; (void)ws_size;
  const float* hid_r  = (const float*)d_in[0];
  const float* in_mask= (const float*)d_in[1];
  const float* init_in= (const float*)d_in[2];
  const float* h0     = (const float*)d_in[3];
  const float* c0     = (const float*)d_in[4];
  const float* W1     = (const float*)d_in[5];
  const float* b1     = (const float*)d_in[6];
  const float* Wih    = (const float*)d_in[7];
  const float* Whh    = (const float*)d_in[8];
  const float* bih    = (const float*)d_in[9];
  const float* bhh    = (const float*)d_in[10];
  const float* W2     = (const float*)d_in[11];
  const float* b2     = (const float*)d_in[12];
  const float* Wq     = (const float*)d_in[13];
  const float* bq     = (const float*)d_in[14];
  const float* Wk     = (const float*)d_in[15];
  const float* bk     = (const float*)d_in[16];
  const float* Wv     = (const float*)d_in[17];
  const float* bv     = (const float*)d_in[18];
  const float* W3     = (const float*)d_in[19];
  const float* b3     = (const float*)d_in[20];
  char* ws = (char*)d_ws;
  float* out = (float*)d_out;

  hipLaunchKernelGGL(kPrep, dim3(410), dim3(256), 0, stream, ws,
                     W1, Wih, Whh, W2, Wq, bq, Wk, bk, Wv, bv, W3, b3, bih, bhh, c0, h0);
  hipLaunchKernelGGL(kKTVW, dim3(2048), dim3(256), 0, stream, ws, hid_r, in_mask);
  for (int s = 0; s < 1024; ++s) {
    hipLaunchKernelGGL(kA, dim3(128), dim3(1024), 0, stream, ws, init_in, in_mask, b1, out, s);
    hipLaunchKernelGGL(kB, dim3(512), dim3(512), 0, stream, ws, b2, s);
  }
  hipLaunchKernelGGL(kWLast, dim3(64), dim3(1024), 0, stream, ws, in_mask, out);
}